// Round 1
// baseline (1251.935 us; speedup 1.0000x reference)
//
#include <hip/hip_runtime.h>
#include <hip/hip_fp16.h>

#define B_ 256
#define T_ 512
#define D_ 64
#define H_ 128

template <typename AT> __device__ inline AT toAT(float x);
template <> __device__ inline float toAT<float>(float x) { return x; }
template <> __device__ inline __half toAT<__half>(float x) { return __float2half(x); }
__device__ inline float toF(float x) { return x; }
__device__ inline float toF(__half x) { return __half2float(x); }

// ---------------------------------------------------------------------------
// Kernel 1: precompute per-(b,t) pre-activations for the 4 "gates":
//   gate 0: A_g = dlt @ w_gamma_h + b_gamma_h
//   gate 1: A_z = x_eff @ w_zx + m @ w_zm + b_z
//   gate 2: A_r = x_eff @ w_rx + m @ w_rm + b_r
//   gate 3: A_h = x_eff @ w_hx + m @ w_hm + b_h
// where x_eff = m*v + (1-m)*(gx*xl + (1-gx)*mean), gx = exp(-relu(wgx*dlt+bgx))
// Output layout: A[row][4][H], row = b*T + t   (row stride 512 floats)
// ---------------------------------------------------------------------------
template <typename AT>
__global__ __launch_bounds__(256) void grud_pre(
    const float* __restrict__ values, const float* __restrict__ masks,
    const float* __restrict__ deltas, const float* __restrict__ emean,
    const float* __restrict__ locf,
    const float* __restrict__ w_gamma_x, const float* __restrict__ w_gamma_h,
    const float* __restrict__ w_rx, const float* __restrict__ w_rm,
    const float* __restrict__ w_zx, const float* __restrict__ w_zm,
    const float* __restrict__ w_hx, const float* __restrict__ w_hm,
    const float* __restrict__ b_gamma_x, const float* __restrict__ b_gamma_h,
    const float* __restrict__ b_r, const float* __restrict__ b_z,
    const float* __restrict__ b_h, AT* __restrict__ A) {
  __shared__ __align__(16) float xs[64][64];   // x_eff tile (or dlt for gate 0)
  __shared__ __align__(16) float ms_[64][64];  // mask tile
  __shared__ float c_wg[64], c_bg[64], c_mn[64];

  const int tid = threadIdx.x;
  const int gate = blockIdx.y;
  const int rowbase = blockIdx.x * 64;
  const size_t base = (size_t)rowbase * D_;

  if (gate == 0) {
    const float4* dp = (const float4*)(deltas + base);
    for (int i = tid; i < 1024; i += 256) ((float4*)&xs[0][0])[i] = dp[i];
  } else {
    if (tid < 64) {
      c_wg[tid] = w_gamma_x[tid];
      c_bg[tid] = b_gamma_x[tid];
      c_mn[tid] = emean[tid];
    }
    __syncthreads();
    const float4* vp = (const float4*)(values + base);
    const float4* mp = (const float4*)(masks + base);
    const float4* dp = (const float4*)(deltas + base);
    const float4* lp = (const float4*)(locf + base);
    for (int i = tid; i < 1024; i += 256) {
      float4 v = vp[i], m = mp[i], dl = dp[i], l = lp[i];
      const int d0 = (i & 15) * 4;
      float vv[4] = {v.x, v.y, v.z, v.w};
      float mm[4] = {m.x, m.y, m.z, m.w};
      float dd[4] = {dl.x, dl.y, dl.z, dl.w};
      float ll[4] = {l.x, l.y, l.z, l.w};
      float xo[4];
#pragma unroll
      for (int j = 0; j < 4; ++j) {
        const int d = d0 + j;
        float gx = expf(-fmaxf(c_wg[d] * dd[j] + c_bg[d], 0.f));
        xo[j] = mm[j] * vv[j] + (1.f - mm[j]) * (gx * ll[j] + (1.f - gx) * c_mn[d]);
      }
      ((float4*)&xs[0][0])[i] = make_float4(xo[0], xo[1], xo[2], xo[3]);
      ((float4*)&ms_[0][0])[i] = m;
    }
  }
  __syncthreads();

  const int col = tid & 127;
  const int rset = tid >> 7;
  const float* Wx;
  const float* Wm = nullptr;
  const float* bias;
  if (gate == 0) {
    Wx = w_gamma_h; bias = b_gamma_h;
  } else if (gate == 1) {
    Wx = w_zx; Wm = w_zm; bias = b_z;
  } else if (gate == 2) {
    Wx = w_rx; Wm = w_rm; bias = b_r;
  } else {
    Wx = w_hx; Wm = w_hm; bias = b_h;
  }

  float wx[64], wm[64];
#pragma unroll
  for (int k = 0; k < 64; ++k) wx[k] = Wx[k * H_ + col];
  if (gate != 0) {
#pragma unroll
    for (int k = 0; k < 64; ++k) wm[k] = Wm[k * H_ + col];
  }
  const float bv = bias[col];

  for (int r = 0; r < 32; ++r) {
    const int row = rset * 32 + r;
    float a0 = 0.f, a1 = 0.f, a2 = 0.f, a3 = 0.f;
    if (gate == 0) {
#pragma unroll
      for (int k4 = 0; k4 < 16; ++k4) {
        float4 xv = *(const float4*)&xs[row][k4 * 4];
        a0 += xv.x * wx[k4 * 4 + 0];
        a1 += xv.y * wx[k4 * 4 + 1];
        a2 += xv.z * wx[k4 * 4 + 2];
        a3 += xv.w * wx[k4 * 4 + 3];
      }
    } else {
#pragma unroll
      for (int k4 = 0; k4 < 16; ++k4) {
        float4 xv = *(const float4*)&xs[row][k4 * 4];
        float4 mv = *(const float4*)&ms_[row][k4 * 4];
        a0 += xv.x * wx[k4 * 4 + 0] + mv.x * wm[k4 * 4 + 0];
        a1 += xv.y * wx[k4 * 4 + 1] + mv.y * wm[k4 * 4 + 1];
        a2 += xv.z * wx[k4 * 4 + 2] + mv.z * wm[k4 * 4 + 2];
        a3 += xv.w * wx[k4 * 4 + 3] + mv.w * wm[k4 * 4 + 3];
      }
    }
    const float acc = bv + ((a0 + a1) + (a2 + a3));
    A[(size_t)(rowbase + row) * (4 * H_) + gate * H_ + col] = toAT<AT>(acc);
  }
}

// ---------------------------------------------------------------------------
// Kernel 2: sequential recurrence. One block per batch element.
// 256 threads = (kh in {0,1}) x (col in 0..127).
// Recurrent weights (3 x 128x128 fp32) live in registers: 192 VGPR/thread.
// h state in LDS (128 floats), invariant at loop top: h_lds = gamma_h(t)*h_{t-1}
// ---------------------------------------------------------------------------
template <typename AT>
__global__ __launch_bounds__(256, 1) void grud_rec(
    const AT* __restrict__ A, const float* __restrict__ w_zh,
    const float* __restrict__ w_rh, const float* __restrict__ w_hh,
    float* __restrict__ hid, float* __restrict__ hlast) {
  const int b = blockIdx.x;
  const int tid = threadIdx.x;
  const int kh = tid >> 7;
  const int col = tid & 127;
  const int krow = kh * 64;

  __shared__ __align__(16) float h_lds[H_];
  __shared__ __align__(16) float rh_lds[H_];
  __shared__ float pz[2][H_], pr[2][H_], ph[2][H_];

  float wz[64], wr[64], wh[64];
#pragma unroll
  for (int k = 0; k < 64; ++k) {
    wz[k] = w_zh[(krow + k) * H_ + col];
    wr[k] = w_rh[(krow + k) * H_ + col];
    wh[k] = w_hh[(krow + k) * H_ + col];
  }
  if (kh == 0) h_lds[col] = 0.f;

  float ag = 0.f, az = 0.f, ar = 0.f, ah = 0.f;
  if (kh == 0) {
    const AT* ap = A + (size_t)b * T_ * (4 * H_) + col;
    ag = toF(ap[0]); az = toF(ap[H_]); ar = toF(ap[2 * H_]); ah = toF(ap[3 * H_]);
  }
  __syncthreads();

  for (int t = 0; t < T_; ++t) {
    // prefetch next step's pre-activations (hide HBM latency under matvecs)
    float nag = 0.f, naz = 0.f, nar = 0.f, nah = 0.f;
    if (kh == 0) {
      const int tn = (t < T_ - 1) ? t + 1 : t;
      const AT* ap = A + ((size_t)b * T_ + tn) * (4 * H_) + col;
      nag = toF(ap[0]); naz = toF(ap[H_]); nar = toF(ap[2 * H_]); nah = toF(ap[3 * H_]);
    }

    // z/r matvecs on h_lds (= gamma_h(t) * h_{t-1})
    float z0 = 0.f, z1 = 0.f, z2 = 0.f, z3 = 0.f;
    float r0 = 0.f, r1 = 0.f, r2 = 0.f, r3 = 0.f;
#pragma unroll
    for (int k4 = 0; k4 < 16; ++k4) {
      float4 hv = *(const float4*)&h_lds[krow + k4 * 4];
      z0 += hv.x * wz[k4 * 4 + 0]; z1 += hv.y * wz[k4 * 4 + 1];
      z2 += hv.z * wz[k4 * 4 + 2]; z3 += hv.w * wz[k4 * 4 + 3];
      r0 += hv.x * wr[k4 * 4 + 0]; r1 += hv.y * wr[k4 * 4 + 1];
      r2 += hv.z * wr[k4 * 4 + 2]; r3 += hv.w * wr[k4 * 4 + 3];
    }
    pz[kh][col] = (z0 + z1) + (z2 + z3);
    pr[kh][col] = (r0 + r1) + (r2 + r3);
    __syncthreads();

    float zz = 0.f, hsc = 0.f;
    if (kh == 0) {
      zz = 1.f / (1.f + expf(-(az + pz[0][col] + pz[1][col])));
      float rr = 1.f / (1.f + expf(-(ar + pr[0][col] + pr[1][col])));
      hsc = h_lds[col];
      rh_lds[col] = rr * hsc;
    }
    __syncthreads();

    // h_tilde matvec on r*h
    float h0 = 0.f, h1 = 0.f, h2 = 0.f, h3 = 0.f;
#pragma unroll
    for (int k4 = 0; k4 < 16; ++k4) {
      float4 rv = *(const float4*)&rh_lds[krow + k4 * 4];
      h0 += rv.x * wh[k4 * 4 + 0]; h1 += rv.y * wh[k4 * 4 + 1];
      h2 += rv.z * wh[k4 * 4 + 2]; h3 += rv.w * wh[k4 * 4 + 3];
    }
    ph[kh][col] = (h0 + h1) + (h2 + h3);
    __syncthreads();

    if (kh == 0) {
      float ht = tanhf(ah + ph[0][col] + ph[1][col]);
      float hn = (1.f - zz) * hsc + zz * ht;
      hid[((size_t)b * T_ + t) * H_ + col] = hn;
      if (t == T_ - 1) hlast[(size_t)b * H_ + col] = hn;
      // fold next step's gamma_h scaling into the state write
      float ghn = (t < T_ - 1) ? expf(-fmaxf(nag, 0.f)) : 1.f;
      h_lds[col] = hn * ghn;
      ag = nag; az = naz; ar = nar; ah = nah;
    }
    __syncthreads();
  }
}

extern "C" void kernel_launch(void* const* d_in, const int* in_sizes, int n_in,
                              void* d_out, int out_size, void* d_ws, size_t ws_size,
                              hipStream_t stream) {
  const float* values = (const float*)d_in[0];
  const float* masks = (const float*)d_in[1];
  const float* deltas = (const float*)d_in[2];
  const float* emean = (const float*)d_in[3];
  const float* locf = (const float*)d_in[4];
  const float* w_gamma_x = (const float*)d_in[5];
  const float* w_gamma_h = (const float*)d_in[6];
  const float* w_rx = (const float*)d_in[7];
  const float* w_rh = (const float*)d_in[8];
  const float* w_rm = (const float*)d_in[9];
  const float* w_zx = (const float*)d_in[10];
  const float* w_zh = (const float*)d_in[11];
  const float* w_zm = (const float*)d_in[12];
  const float* w_hx = (const float*)d_in[13];
  const float* w_hh = (const float*)d_in[14];
  const float* w_hm = (const float*)d_in[15];
  const float* b_gamma_x = (const float*)d_in[16];
  const float* b_gamma_h = (const float*)d_in[17];
  const float* b_r = (const float*)d_in[18];
  const float* b_z = (const float*)d_in[19];
  const float* b_h = (const float*)d_in[20];

  float* hid = (float*)d_out;
  float* hlast = hid + (size_t)B_ * T_ * H_;

  dim3 gpre(B_ * T_ / 64, 4), bpre(256);
  dim3 grec(B_), brec(256);

  const size_t needF = (size_t)B_ * T_ * 4 * H_ * sizeof(float);
  if (ws_size >= needF) {
    float* A = (float*)d_ws;
    grud_pre<float><<<gpre, bpre, 0, stream>>>(
        values, masks, deltas, emean, locf, w_gamma_x, w_gamma_h, w_rx, w_rm,
        w_zx, w_zm, w_hx, w_hm, b_gamma_x, b_gamma_h, b_r, b_z, b_h, A);
    grud_rec<float><<<grec, brec, 0, stream>>>(A, w_zh, w_rh, w_hh, hid, hlast);
  } else {
    __half* A = (__half*)d_ws;
    grud_pre<__half><<<gpre, bpre, 0, stream>>>(
        values, masks, deltas, emean, locf, w_gamma_x, w_gamma_h, w_rx, w_rm,
        w_zx, w_zm, w_hx, w_hm, b_gamma_x, b_gamma_h, b_r, b_z, b_h, A);
    grud_rec<__half><<<grec, brec, 0, stream>>>(A, w_zh, w_rh, w_hh, hid, hlast);
  }
}

// Round 2
// 960.026 us; speedup vs baseline: 1.3041x; 1.3041x over previous
//
#include <hip/hip_runtime.h>
#include <hip/hip_fp16.h>

#define B_ 256
#define T_ 512
#define D_ 64
#define H_ 128

template <typename AT> __device__ inline AT toAT(float x);
template <> __device__ inline float toAT<float>(float x) { return x; }
template <> __device__ inline __half toAT<__half>(float x) { return __float2half(x); }
__device__ inline float toF(float x) { return x; }
__device__ inline float toF(__half x) { return __half2float(x); }

__device__ inline float fsig(float x) {
  // sigmoid(x) = 1/(1+e^-x); v_exp + v_rcp fast path
  return __builtin_amdgcn_rcpf(1.f + __expf(-x));
}
__device__ inline float ftanh(float x) {
  // tanh(x) = 1 - 2/(e^{2x}+1); saturates correctly at +-inf
  return 1.f - 2.f * __builtin_amdgcn_rcpf(1.f + __expf(2.f * x));
}

// ---------------------------------------------------------------------------
// Kernel 1: precompute per-(b,t) pre-activations for the 4 "gates":
//   gate 0: G   = exp(-relu(dlt @ w_gamma_h + b_gamma_h))   (pre-exponentiated!)
//   gate 1: A_z = x_eff @ w_zx + m @ w_zm + b_z
//   gate 2: A_r = x_eff @ w_rx + m @ w_rm + b_r
//   gate 3: A_h = x_eff @ w_hx + m @ w_hm + b_h
// where x_eff = m*v + (1-m)*(gx*xl + (1-gx)*mean), gx = exp(-relu(wgx*dlt+bgx))
// Output layout: A[row][4][H], row = b*T + t   (row stride 512 elements)
// ---------------------------------------------------------------------------
template <typename AT>
__global__ __launch_bounds__(256) void grud_pre(
    const float* __restrict__ values, const float* __restrict__ masks,
    const float* __restrict__ deltas, const float* __restrict__ emean,
    const float* __restrict__ locf,
    const float* __restrict__ w_gamma_x, const float* __restrict__ w_gamma_h,
    const float* __restrict__ w_rx, const float* __restrict__ w_rm,
    const float* __restrict__ w_zx, const float* __restrict__ w_zm,
    const float* __restrict__ w_hx, const float* __restrict__ w_hm,
    const float* __restrict__ b_gamma_x, const float* __restrict__ b_gamma_h,
    const float* __restrict__ b_r, const float* __restrict__ b_z,
    const float* __restrict__ b_h, AT* __restrict__ A) {
  __shared__ __align__(16) float xs[64][64];   // x_eff tile (or dlt for gate 0)
  __shared__ __align__(16) float ms_[64][64];  // mask tile
  __shared__ float c_wg[64], c_bg[64], c_mn[64];

  const int tid = threadIdx.x;
  const int gate = blockIdx.y;
  const int rowbase = blockIdx.x * 64;
  const size_t base = (size_t)rowbase * D_;

  if (gate == 0) {
    const float4* dp = (const float4*)(deltas + base);
    for (int i = tid; i < 1024; i += 256) ((float4*)&xs[0][0])[i] = dp[i];
  } else {
    if (tid < 64) {
      c_wg[tid] = w_gamma_x[tid];
      c_bg[tid] = b_gamma_x[tid];
      c_mn[tid] = emean[tid];
    }
    __syncthreads();
    const float4* vp = (const float4*)(values + base);
    const float4* mp = (const float4*)(masks + base);
    const float4* dp = (const float4*)(deltas + base);
    const float4* lp = (const float4*)(locf + base);
    for (int i = tid; i < 1024; i += 256) {
      float4 v = vp[i], m = mp[i], dl = dp[i], l = lp[i];
      const int d0 = (i & 15) * 4;
      float vv[4] = {v.x, v.y, v.z, v.w};
      float mm[4] = {m.x, m.y, m.z, m.w};
      float dd[4] = {dl.x, dl.y, dl.z, dl.w};
      float ll[4] = {l.x, l.y, l.z, l.w};
      float xo[4];
#pragma unroll
      for (int j = 0; j < 4; ++j) {
        const int d = d0 + j;
        float gx = __expf(-fmaxf(c_wg[d] * dd[j] + c_bg[d], 0.f));
        xo[j] = mm[j] * vv[j] + (1.f - mm[j]) * (gx * ll[j] + (1.f - gx) * c_mn[d]);
      }
      ((float4*)&xs[0][0])[i] = make_float4(xo[0], xo[1], xo[2], xo[3]);
      ((float4*)&ms_[0][0])[i] = m;
    }
  }
  __syncthreads();

  const int col = tid & 127;
  const int rset = tid >> 7;
  const float* Wx;
  const float* Wm = nullptr;
  const float* bias;
  if (gate == 0) {
    Wx = w_gamma_h; bias = b_gamma_h;
  } else if (gate == 1) {
    Wx = w_zx; Wm = w_zm; bias = b_z;
  } else if (gate == 2) {
    Wx = w_rx; Wm = w_rm; bias = b_r;
  } else {
    Wx = w_hx; Wm = w_hm; bias = b_h;
  }

  float wx[64], wm[64];
#pragma unroll
  for (int k = 0; k < 64; ++k) wx[k] = Wx[k * H_ + col];
  if (gate != 0) {
#pragma unroll
    for (int k = 0; k < 64; ++k) wm[k] = Wm[k * H_ + col];
  }
  const float bv = bias[col];

  for (int r = 0; r < 32; ++r) {
    const int row = rset * 32 + r;
    float a0 = 0.f, a1 = 0.f, a2 = 0.f, a3 = 0.f;
    if (gate == 0) {
#pragma unroll
      for (int k4 = 0; k4 < 16; ++k4) {
        float4 xv = *(const float4*)&xs[row][k4 * 4];
        a0 += xv.x * wx[k4 * 4 + 0];
        a1 += xv.y * wx[k4 * 4 + 1];
        a2 += xv.z * wx[k4 * 4 + 2];
        a3 += xv.w * wx[k4 * 4 + 3];
      }
    } else {
#pragma unroll
      for (int k4 = 0; k4 < 16; ++k4) {
        float4 xv = *(const float4*)&xs[row][k4 * 4];
        float4 mv = *(const float4*)&ms_[row][k4 * 4];
        a0 += xv.x * wx[k4 * 4 + 0] + mv.x * wm[k4 * 4 + 0];
        a1 += xv.y * wx[k4 * 4 + 1] + mv.y * wm[k4 * 4 + 1];
        a2 += xv.z * wx[k4 * 4 + 2] + mv.z * wm[k4 * 4 + 2];
        a3 += xv.w * wx[k4 * 4 + 3] + mv.w * wm[k4 * 4 + 3];
      }
    }
    float acc = bv + ((a0 + a1) + (a2 + a3));
    if (gate == 0) acc = __expf(-fmaxf(acc, 0.f));  // pre-exponentiate gamma_h
    A[(size_t)(rowbase + row) * (4 * H_) + gate * H_ + col] = toAT<AT>(acc);
  }
}

// ---------------------------------------------------------------------------
// Kernel 2: sequential recurrence. One block per batch element.
// 512 threads = (kq in {0..3}) x (col in 0..127)  -> 8 waves (2 per SIMD).
// Each thread holds 32 rows of each recurrent weight matrix: 96 VGPRs.
// h state in LDS; invariant at loop top: h_lds = gamma_h(t) * h_{t-1}.
// Gate math (sigmoid/tanh) done by kq==0 only, with fast exp/rcp.
// ---------------------------------------------------------------------------
template <typename AT>
__global__ __launch_bounds__(512, 2) void grud_rec(
    const AT* __restrict__ A, const float* __restrict__ w_zh,
    const float* __restrict__ w_rh, const float* __restrict__ w_hh,
    float* __restrict__ hid, float* __restrict__ hlast) {
  const int b = blockIdx.x;
  const int tid = threadIdx.x;
  const int kq = tid >> 7;       // 0..3  (k-quarter)
  const int col = tid & 127;
  const int krow = kq * 32;

  __shared__ __align__(16) float h_lds[H_];
  __shared__ __align__(16) float rh_lds[H_];
  __shared__ float pz[4][H_], pr[4][H_], ph[4][H_];

  float wz[32], wr[32], wh[32];
#pragma unroll
  for (int k = 0; k < 32; ++k) {
    wz[k] = w_zh[(krow + k) * H_ + col];
    wr[k] = w_rh[(krow + k) * H_ + col];
    wh[k] = w_hh[(krow + k) * H_ + col];
  }
  if (tid < H_) h_lds[tid] = 0.f;

  const AT* Ab = A + (size_t)b * T_ * (4 * H_);
  float az = 0.f, ar = 0.f, ah = 0.f;   // current step's pre-activations (kq0)
  if (kq == 0) {
    az = toF(Ab[H_ + col]);
    ar = toF(Ab[2 * H_ + col]);
    ah = toF(Ab[3 * H_ + col]);
  }
  __syncthreads();

  float zz = 0.f, hsc = 0.f;
  for (int t = 0; t < T_; ++t) {
    // prefetch t+1 (kq0 only); completes under the two matvec phases
    float nG = 1.f, naz = 0.f, nar = 0.f, nah = 0.f;
    if (kq == 0) {
      const int tn = (t < T_ - 1) ? t + 1 : t;
      const AT* ap = Ab + (size_t)tn * (4 * H_) + col;
      nG = toF(ap[0]); naz = toF(ap[H_]); nar = toF(ap[2 * H_]); nah = toF(ap[3 * H_]);
    }

    // P1: z/r partial matvecs on h_lds (= gamma_h(t) * h_{t-1})
    float z0 = 0.f, z1 = 0.f, z2 = 0.f, z3 = 0.f;
    float r0 = 0.f, r1 = 0.f, r2 = 0.f, r3 = 0.f;
#pragma unroll
    for (int k4 = 0; k4 < 8; ++k4) {
      float4 hv = *(const float4*)&h_lds[krow + k4 * 4];
      z0 += hv.x * wz[k4 * 4 + 0]; z1 += hv.y * wz[k4 * 4 + 1];
      z2 += hv.z * wz[k4 * 4 + 2]; z3 += hv.w * wz[k4 * 4 + 3];
      r0 += hv.x * wr[k4 * 4 + 0]; r1 += hv.y * wr[k4 * 4 + 1];
      r2 += hv.z * wr[k4 * 4 + 2]; r3 += hv.w * wr[k4 * 4 + 3];
    }
    pz[kq][col] = (z0 + z1) + (z2 + z3);
    pr[kq][col] = (r0 + r1) + (r2 + r3);
    __syncthreads();

    // P2: gates z,r (kq0 only, fast transcendentals)
    if (kq == 0) {
      float sz = az + ((pz[0][col] + pz[1][col]) + (pz[2][col] + pz[3][col]));
      float sr = ar + ((pr[0][col] + pr[1][col]) + (pr[2][col] + pr[3][col]));
      zz = fsig(sz);
      float rr = fsig(sr);
      hsc = h_lds[col];
      rh_lds[col] = rr * hsc;
    }
    __syncthreads();

    // P3: h_tilde partial matvec on r*h
    float h0 = 0.f, h1 = 0.f, h2 = 0.f, h3 = 0.f;
#pragma unroll
    for (int k4 = 0; k4 < 8; ++k4) {
      float4 rv = *(const float4*)&rh_lds[krow + k4 * 4];
      h0 += rv.x * wh[k4 * 4 + 0]; h1 += rv.y * wh[k4 * 4 + 1];
      h2 += rv.z * wh[k4 * 4 + 2]; h3 += rv.w * wh[k4 * 4 + 3];
    }
    ph[kq][col] = (h0 + h1) + (h2 + h3);
    __syncthreads();

    // P4: blend + state update (kq0 only)
    if (kq == 0) {
      float sh = ah + ((ph[0][col] + ph[1][col]) + (ph[2][col] + ph[3][col]));
      float ht = ftanh(sh);
      float hn = (1.f - zz) * hsc + zz * ht;
      hid[((size_t)b * T_ + t) * H_ + col] = hn;
      if (t == T_ - 1) hlast[(size_t)b * H_ + col] = hn;
      // fold next step's gamma_h scaling into the state write (pre-exp'd G)
      h_lds[col] = (t < T_ - 1) ? hn * nG : hn;
      az = naz; ar = nar; ah = nah;
    }
    __syncthreads();
  }
}

extern "C" void kernel_launch(void* const* d_in, const int* in_sizes, int n_in,
                              void* d_out, int out_size, void* d_ws, size_t ws_size,
                              hipStream_t stream) {
  const float* values = (const float*)d_in[0];
  const float* masks = (const float*)d_in[1];
  const float* deltas = (const float*)d_in[2];
  const float* emean = (const float*)d_in[3];
  const float* locf = (const float*)d_in[4];
  const float* w_gamma_x = (const float*)d_in[5];
  const float* w_gamma_h = (const float*)d_in[6];
  const float* w_rx = (const float*)d_in[7];
  const float* w_rh = (const float*)d_in[8];
  const float* w_rm = (const float*)d_in[9];
  const float* w_zx = (const float*)d_in[10];
  const float* w_zh = (const float*)d_in[11];
  const float* w_zm = (const float*)d_in[12];
  const float* w_hx = (const float*)d_in[13];
  const float* w_hh = (const float*)d_in[14];
  const float* w_hm = (const float*)d_in[15];
  const float* b_gamma_x = (const float*)d_in[16];
  const float* b_gamma_h = (const float*)d_in[17];
  const float* b_r = (const float*)d_in[18];
  const float* b_z = (const float*)d_in[19];
  const float* b_h = (const float*)d_in[20];

  float* hid = (float*)d_out;
  float* hlast = hid + (size_t)B_ * T_ * H_;

  dim3 gpre(B_ * T_ / 64, 4), bpre(256);
  dim3 grec(B_), brec(512);

  const size_t needH = (size_t)B_ * T_ * 4 * H_ * sizeof(__half);
  const size_t needF = (size_t)B_ * T_ * 4 * H_ * sizeof(float);
  if (ws_size >= needH) {
    __half* A = (__half*)d_ws;
    grud_pre<__half><<<gpre, bpre, 0, stream>>>(
        values, masks, deltas, emean, locf, w_gamma_x, w_gamma_h, w_rx, w_rm,
        w_zx, w_zm, w_hx, w_hm, b_gamma_x, b_gamma_h, b_r, b_z, b_h, A);
    grud_rec<__half><<<grec, brec, 0, stream>>>(A, w_zh, w_rh, w_hh, hid, hlast);
  } else if (ws_size >= needF) {
    float* A = (float*)d_ws;
    grud_pre<float><<<gpre, bpre, 0, stream>>>(
        values, masks, deltas, emean, locf, w_gamma_x, w_gamma_h, w_rx, w_rm,
        w_zx, w_zm, w_hx, w_hm, b_gamma_x, b_gamma_h, b_r, b_z, b_h, A);
    grud_rec<float><<<grec, brec, 0, stream>>>(A, w_zh, w_rh, w_hh, hid, hlast);
  }
}

// Round 3
// 768.093 us; speedup vs baseline: 1.6299x; 1.2499x over previous
//
#include <hip/hip_runtime.h>
#include <hip/hip_fp16.h>

#define B_ 256
#define T_ 512
#define D_ 64
#define H_ 128

template <typename AT> __device__ inline AT toAT(float x);
template <> __device__ inline float toAT<float>(float x) { return x; }
template <> __device__ inline __half toAT<__half>(float x) { return __float2half(x); }
__device__ inline float toF(float x) { return x; }
__device__ inline float toF(__half x) { return __half2float(x); }

__device__ inline float fsig(float x) {
  return __builtin_amdgcn_rcpf(1.f + __expf(-x));
}
__device__ inline float ftanh(float x) {
  return 1.f - 2.f * __builtin_amdgcn_rcpf(1.f + __expf(2.f * x));
}

// ---------------------------------------------------------------------------
// Kernel 1 (unchanged from r2): per-(b,t) pre-activations, layout A[row][4][H]
//   gate 0: G   = exp(-relu(dlt @ w_gamma_h + b_gamma_h))   (pre-exponentiated)
//   gate 1: A_z, gate 2: A_r, gate 3: A_h
// ---------------------------------------------------------------------------
template <typename AT>
__global__ __launch_bounds__(256) void grud_pre(
    const float* __restrict__ values, const float* __restrict__ masks,
    const float* __restrict__ deltas, const float* __restrict__ emean,
    const float* __restrict__ locf,
    const float* __restrict__ w_gamma_x, const float* __restrict__ w_gamma_h,
    const float* __restrict__ w_rx, const float* __restrict__ w_rm,
    const float* __restrict__ w_zx, const float* __restrict__ w_zm,
    const float* __restrict__ w_hx, const float* __restrict__ w_hm,
    const float* __restrict__ b_gamma_x, const float* __restrict__ b_gamma_h,
    const float* __restrict__ b_r, const float* __restrict__ b_z,
    const float* __restrict__ b_h, AT* __restrict__ A) {
  __shared__ __align__(16) float xs[64][64];
  __shared__ __align__(16) float ms_[64][64];
  __shared__ float c_wg[64], c_bg[64], c_mn[64];

  const int tid = threadIdx.x;
  const int gate = blockIdx.y;
  const int rowbase = blockIdx.x * 64;
  const size_t base = (size_t)rowbase * D_;

  if (gate == 0) {
    const float4* dp = (const float4*)(deltas + base);
    for (int i = tid; i < 1024; i += 256) ((float4*)&xs[0][0])[i] = dp[i];
  } else {
    if (tid < 64) {
      c_wg[tid] = w_gamma_x[tid];
      c_bg[tid] = b_gamma_x[tid];
      c_mn[tid] = emean[tid];
    }
    __syncthreads();
    const float4* vp = (const float4*)(values + base);
    const float4* mp = (const float4*)(masks + base);
    const float4* dp = (const float4*)(deltas + base);
    const float4* lp = (const float4*)(locf + base);
    for (int i = tid; i < 1024; i += 256) {
      float4 v = vp[i], m = mp[i], dl = dp[i], l = lp[i];
      const int d0 = (i & 15) * 4;
      float vv[4] = {v.x, v.y, v.z, v.w};
      float mm[4] = {m.x, m.y, m.z, m.w};
      float dd[4] = {dl.x, dl.y, dl.z, dl.w};
      float ll[4] = {l.x, l.y, l.z, l.w};
      float xo[4];
#pragma unroll
      for (int j = 0; j < 4; ++j) {
        const int d = d0 + j;
        float gx = __expf(-fmaxf(c_wg[d] * dd[j] + c_bg[d], 0.f));
        xo[j] = mm[j] * vv[j] + (1.f - mm[j]) * (gx * ll[j] + (1.f - gx) * c_mn[d]);
      }
      ((float4*)&xs[0][0])[i] = make_float4(xo[0], xo[1], xo[2], xo[3]);
      ((float4*)&ms_[0][0])[i] = m;
    }
  }
  __syncthreads();

  const int col = tid & 127;
  const int rset = tid >> 7;
  const float* Wx;
  const float* Wm = nullptr;
  const float* bias;
  if (gate == 0) {
    Wx = w_gamma_h; bias = b_gamma_h;
  } else if (gate == 1) {
    Wx = w_zx; Wm = w_zm; bias = b_z;
  } else if (gate == 2) {
    Wx = w_rx; Wm = w_rm; bias = b_r;
  } else {
    Wx = w_hx; Wm = w_hm; bias = b_h;
  }

  float wx[64], wm[64];
#pragma unroll
  for (int k = 0; k < 64; ++k) wx[k] = Wx[k * H_ + col];
  if (gate != 0) {
#pragma unroll
    for (int k = 0; k < 64; ++k) wm[k] = Wm[k * H_ + col];
  }
  const float bv = bias[col];

  for (int r = 0; r < 32; ++r) {
    const int row = rset * 32 + r;
    float a0 = 0.f, a1 = 0.f, a2 = 0.f, a3 = 0.f;
    if (gate == 0) {
#pragma unroll
      for (int k4 = 0; k4 < 16; ++k4) {
        float4 xv = *(const float4*)&xs[row][k4 * 4];
        a0 += xv.x * wx[k4 * 4 + 0];
        a1 += xv.y * wx[k4 * 4 + 1];
        a2 += xv.z * wx[k4 * 4 + 2];
        a3 += xv.w * wx[k4 * 4 + 3];
      }
    } else {
#pragma unroll
      for (int k4 = 0; k4 < 16; ++k4) {
        float4 xv = *(const float4*)&xs[row][k4 * 4];
        float4 mv = *(const float4*)&ms_[row][k4 * 4];
        a0 += xv.x * wx[k4 * 4 + 0] + mv.x * wm[k4 * 4 + 0];
        a1 += xv.y * wx[k4 * 4 + 1] + mv.y * wm[k4 * 4 + 1];
        a2 += xv.z * wx[k4 * 4 + 2] + mv.z * wm[k4 * 4 + 2];
        a3 += xv.w * wx[k4 * 4 + 3] + mv.w * wm[k4 * 4 + 3];
      }
    }
    float acc = bv + ((a0 + a1) + (a2 + a3));
    if (gate == 0) acc = __expf(-fmaxf(acc, 0.f));
    A[(size_t)(rowbase + row) * (4 * H_) + gate * H_ + col] = toAT<AT>(acc);
  }
}

// ---------------------------------------------------------------------------
// Kernel 2: sequential recurrence. One block per batch element.
// 512 threads, tid = col*4 + kq  ->  a wave holds 16 cols x 4 k-quarters.
// k-reduction is intra-wave (2x shfl_xor over lane bits 0..1) -> no LDS
// round trip; gate math computed redundantly by all 4 kq lanes.
// 2 barriers/step: publish r*h, publish h.
// Weights: float4 arrays, compile-time indexed; k-order rotated by kq so the
// 4 kq groups hit disjoint LDS bank quads (conflict-free h/rh reads).
// ---------------------------------------------------------------------------
template <typename AT>
__global__ __launch_bounds__(512, 1) void grud_rec(
    const AT* __restrict__ A, const float* __restrict__ w_zh,
    const float* __restrict__ w_rh, const float* __restrict__ w_hh,
    float* __restrict__ hid, float* __restrict__ hlast) {
  const int b = blockIdx.x;
  const int tid = threadIdx.x;
  const int col = tid >> 2;   // 0..127
  const int kq = tid & 3;     // 0..3
  const int krow = kq * 32;

  __shared__ __align__(16) float h_lds[H_];
  __shared__ __align__(16) float rh_lds[H_];

  // per-thread weight fragments, k-rotated: slot i holds rows krow+rot(i)*4..+3
  float4 wzv[8], wrv[8], whv[8];
#pragma unroll
  for (int i = 0; i < 8; ++i) {
    const int rot = ((i + kq * 2) & 7) * 4;
    const int r0 = krow + rot;
    wzv[i] = make_float4(w_zh[(r0 + 0) * H_ + col], w_zh[(r0 + 1) * H_ + col],
                         w_zh[(r0 + 2) * H_ + col], w_zh[(r0 + 3) * H_ + col]);
    wrv[i] = make_float4(w_rh[(r0 + 0) * H_ + col], w_rh[(r0 + 1) * H_ + col],
                         w_rh[(r0 + 2) * H_ + col], w_rh[(r0 + 3) * H_ + col]);
    whv[i] = make_float4(w_hh[(r0 + 0) * H_ + col], w_hh[(r0 + 1) * H_ + col],
                         w_hh[(r0 + 2) * H_ + col], w_hh[(r0 + 3) * H_ + col]);
  }
  if (tid < H_) h_lds[tid] = 0.f;

  const AT* Ab = A + (size_t)b * T_ * (4 * H_);
  // current-step pre-activations; G prefetched one step further ahead
  float cz = toF(Ab[H_ + col]);
  float cr = toF(Ab[2 * H_ + col]);
  float ch = toF(Ab[3 * H_ + col]);
  float gN = toF(Ab[(size_t)((T_ > 1) ? 1 : 0) * (4 * H_) + col]);  // G[1]
  __syncthreads();

  for (int t = 0; t < T_; ++t) {
    // prefetch: z/r/h for t+1, G for t+2
    const int t1 = (t + 1 < T_) ? t + 1 : T_ - 1;
    const int t2 = (t + 2 < T_) ? t + 2 : T_ - 1;
    const AT* a1 = Ab + (size_t)t1 * (4 * H_);
    const float nz = toF(a1[H_ + col]);
    const float nr = toF(a1[2 * H_ + col]);
    const float nh = toF(a1[3 * H_ + col]);
    const float gF = toF(Ab[(size_t)t2 * (4 * H_) + col]);

    // P1: z/r partial matvecs over h_lds[krow..krow+31] (kq-rotated order)
    float z0 = 0.f, z1 = 0.f, z2 = 0.f, z3 = 0.f;
    float r0 = 0.f, r1 = 0.f, r2 = 0.f, r3 = 0.f;
#pragma unroll
    for (int i = 0; i < 8; ++i) {
      const int rot = ((i + kq * 2) & 7) * 4;
      float4 hv = *(const float4*)&h_lds[krow + rot];
      z0 += hv.x * wzv[i].x; z1 += hv.y * wzv[i].y;
      z2 += hv.z * wzv[i].z; z3 += hv.w * wzv[i].w;
      r0 += hv.x * wrv[i].x; r1 += hv.y * wrv[i].y;
      r2 += hv.z * wrv[i].z; r3 += hv.w * wrv[i].w;
    }
    float pzv = (z0 + z1) + (z2 + z3);
    float prv = (r0 + r1) + (r2 + r3);
    pzv += __shfl_xor(pzv, 1); pzv += __shfl_xor(pzv, 2);
    prv += __shfl_xor(prv, 1); prv += __shfl_xor(prv, 2);

    const float hsc = h_lds[col];
    const float zz = fsig(cz + pzv);
    const float rr = fsig(cr + prv);
    if (kq == 0) rh_lds[col] = rr * hsc;
    __syncthreads();

    // P3: h_tilde partial matvec over rh_lds
    float h0 = 0.f, h1 = 0.f, h2 = 0.f, h3 = 0.f;
#pragma unroll
    for (int i = 0; i < 8; ++i) {
      const int rot = ((i + kq * 2) & 7) * 4;
      float4 rv = *(const float4*)&rh_lds[krow + rot];
      h0 += rv.x * whv[i].x; h1 += rv.y * whv[i].y;
      h2 += rv.z * whv[i].z; h3 += rv.w * whv[i].w;
    }
    float phv = (h0 + h1) + (h2 + h3);
    phv += __shfl_xor(phv, 1); phv += __shfl_xor(phv, 2);

    const float ht = ftanh(ch + phv);
    const float hn = (1.f - zz) * hsc + zz * ht;
    if (kq == 0) {
      hid[((size_t)b * T_ + t) * H_ + col] = hn;
      if (t == T_ - 1) hlast[(size_t)b * H_ + col] = hn;
      h_lds[col] = (t < T_ - 1) ? hn * gN : hn;  // fold gamma_h(t+1)
    }
    cz = nz; cr = nr; ch = nh; gN = gF;
    __syncthreads();
  }
}

extern "C" void kernel_launch(void* const* d_in, const int* in_sizes, int n_in,
                              void* d_out, int out_size, void* d_ws, size_t ws_size,
                              hipStream_t stream) {
  const float* values = (const float*)d_in[0];
  const float* masks = (const float*)d_in[1];
  const float* deltas = (const float*)d_in[2];
  const float* emean = (const float*)d_in[3];
  const float* locf = (const float*)d_in[4];
  const float* w_gamma_x = (const float*)d_in[5];
  const float* w_gamma_h = (const float*)d_in[6];
  const float* w_rx = (const float*)d_in[7];
  const float* w_rh = (const float*)d_in[8];
  const float* w_rm = (const float*)d_in[9];
  const float* w_zx = (const float*)d_in[10];
  const float* w_zh = (const float*)d_in[11];
  const float* w_zm = (const float*)d_in[12];
  const float* w_hx = (const float*)d_in[13];
  const float* w_hh = (const float*)d_in[14];
  const float* w_hm = (const float*)d_in[15];
  const float* b_gamma_x = (const float*)d_in[16];
  const float* b_gamma_h = (const float*)d_in[17];
  const float* b_r = (const float*)d_in[18];
  const float* b_z = (const float*)d_in[19];
  const float* b_h = (const float*)d_in[20];

  float* hid = (float*)d_out;
  float* hlast = hid + (size_t)B_ * T_ * H_;

  dim3 gpre(B_ * T_ / 64, 4), bpre(256);
  dim3 grec(B_), brec(512);

  const size_t needH = (size_t)B_ * T_ * 4 * H_ * sizeof(__half);
  const size_t needF = (size_t)B_ * T_ * 4 * H_ * sizeof(float);
  if (ws_size >= needH) {
    __half* A = (__half*)d_ws;
    grud_pre<__half><<<gpre, bpre, 0, stream>>>(
        values, masks, deltas, emean, locf, w_gamma_x, w_gamma_h, w_rx, w_rm,
        w_zx, w_zm, w_hx, w_hm, b_gamma_x, b_gamma_h, b_r, b_z, b_h, A);
    grud_rec<__half><<<grec, brec, 0, stream>>>(A, w_zh, w_rh, w_hh, hid, hlast);
  } else if (ws_size >= needF) {
    float* A = (float*)d_ws;
    grud_pre<float><<<gpre, bpre, 0, stream>>>(
        values, masks, deltas, emean, locf, w_gamma_x, w_gamma_h, w_rx, w_rm,
        w_zx, w_zm, w_hx, w_hm, b_gamma_x, b_gamma_h, b_r, b_z, b_h, A);
    grud_rec<float><<<grec, brec, 0, stream>>>(A, w_zh, w_rh, w_hh, hid, hlast);
  }
}